// Round 13
// baseline (654.356 us; speedup 1.0000x reference)
//
#include <hip/hip_runtime.h>
#include <hip/hip_cooperative_groups.h>
#include <stdint.h>

namespace cg = cooperative_groups;

#define D 512
#define K_TOT 1024
#define EPS 1e-5f
#define CHUNK 1024

typedef __bf16 bf16;
typedef bf16 bf16x4 __attribute__((ext_vector_type(4)));
typedef bf16 bf16x8 __attribute__((ext_vector_type(8)));
typedef float f32x4 __attribute__((ext_vector_type(4)));

// ---------------- prep: convert x->bf16 (NT loads), zero stat/pads, build Wc ----------------
__global__ void k_prep(const float* __restrict__ x, bf16* __restrict__ xb,
                       float* __restrict__ stat,
                       bf16* __restrict__ padX, bf16* __restrict__ padA,
                       const float* __restrict__ Wl, const float* __restrict__ Wr,
                       bf16* __restrict__ Wc,
                       int padGroups, size_t total8) {
  int gid = blockIdx.x * blockDim.x + threadIdx.x;
  int stride = gridDim.x * blockDim.x;
  if (gid < 2 * D) stat[gid] = 0.f;
  if (gid < padGroups) {
    bf16x8 z = {};
    *(bf16x8*)&padX[(size_t)gid * 8] = z;
    *(bf16x8*)&padA[(size_t)gid * 8] = z;
  }
  // build Wcat[o][k] = k<512 ? W_r[o][k] : W_l[o][k-512]
  for (int w = gid; w < D * K_TOT; w += stride) {
    int o = w >> 10, k = w & 1023;
    float v = (k < D) ? Wr[o * D + k] : Wl[o * D + (k - D)];
    Wc[w] = (bf16)v;
  }
  // x (f32, read-once) -> Xb (bf16): nontemporal loads keep the 205MB stream
  // from evicting the bf16 working set (Xb/csr) out of L3 before k_gather.
  size_t i = (size_t)gid;
  size_t sstride = (size_t)stride;
  const f32x4* xv = (const f32x4*)x;
  for (; i < total8; i += sstride) {
    f32x4 a = __builtin_nontemporal_load(xv + i * 2);
    f32x4 b = __builtin_nontemporal_load(xv + i * 2 + 1);
    bf16x8 v = { (bf16)a[0], (bf16)a[1], (bf16)a[2], (bf16)a[3],
                 (bf16)b[0], (bf16)b[1], (bf16)b[2], (bf16)b[3] };
    *(bf16x8*)&xb[i * 8] = v;
  }
}

// ---------------- cooperative CSR builder: zero -> degree -> scan -> fill, 1 launch ----------------
// Phase bodies are identical to the previously-verified standalone kernels; grid.sync()
// replaces the kernel-boundary ordering. 256 blocks x 256 thr (trivially co-resident).
__global__ void k_csr(const int* __restrict__ src, const int* __restrict__ dst,
                      int* __restrict__ cnt, int* __restrict__ cur,
                      int* __restrict__ offs, int* __restrict__ csr,
                      int* __restrict__ bsum, int* __restrict__ bbase,
                      int n, int E, int nb) {
  cg::grid_group grid = cg::this_grid();
  const int gid = blockIdx.x * blockDim.x + threadIdx.x;
  const int stride = gridDim.x * blockDim.x;
  __shared__ int red[4];
  __shared__ int tsum[256];

  // phase 0: zero cnt, cur
  for (int i = gid; i < n; i += stride) { cnt[i] = 0; cur[i] = 0; }
  grid.sync();

  // phase 1: degree count
  for (int i = gid; i < E; i += stride) atomicAdd(&cnt[dst[i]], 1);
  grid.sync();

  // phase 2: per-chunk sums (block b handles chunk b; nb <= gridDim.x)
  if ((int)blockIdx.x < nb) {
    int base = blockIdx.x * CHUNK;
    int s = 0;
    for (int i = threadIdx.x; i < CHUNK; i += 256) {
      int idx = base + i;
      s += (idx < n) ? cnt[idx] : 0;
    }
#pragma unroll
    for (int o = 32; o > 0; o >>= 1) s += __shfl_down(s, o);
    if ((threadIdx.x & 63) == 0) red[threadIdx.x >> 6] = s;
    __syncthreads();
    if (threadIdx.x == 0) bsum[blockIdx.x] = red[0] + red[1] + red[2] + red[3];
  }
  grid.sync();

  // phase 3: serial scan of chunk sums (1 thread; nb ~ 98)
  if (gid == 0) {
    int run = 0;
    for (int i = 0; i < nb; ++i) { bbase[i] = run; run += bsum[i]; }
    offs[n] = E;
  }
  grid.sync();

  // phase 4: per-chunk exclusive scan + base
  if ((int)blockIdx.x < nb) {
    int b = blockIdx.x;
    int i0 = b * CHUNK + threadIdx.x * 4;
    int vals[4];
    int s = 0;
#pragma unroll
    for (int j = 0; j < 4; ++j) {
      int idx = i0 + j;
      vals[j] = (idx < n) ? cnt[idx] : 0;
      s += vals[j];
    }
    tsum[threadIdx.x] = s;
    __syncthreads();
    for (int d = 1; d < 256; d <<= 1) {
      int v = (threadIdx.x >= (unsigned)d) ? tsum[threadIdx.x - d] : 0;
      __syncthreads();
      tsum[threadIdx.x] += v;
      __syncthreads();
    }
    int excl = tsum[threadIdx.x] - s + bbase[b];
#pragma unroll
    for (int j = 0; j < 4; ++j) {
      int idx = i0 + j;
      if (idx < n) offs[idx] = excl;
      excl += vals[j];
    }
  }
  grid.sync();

  // phase 5: CSR fill (counting sort of src by dst)
  for (int i = gid; i < E; i += stride) {
    int d = dst[i];
    int pos = offs[d] + atomicAdd(&cur[d], 1);
    csr[pos] = src[i];
  }
}

// ---------------- gather (bf16 rows): Aggr[node] = mean of Xb[src], one wave/node ----------------
__device__ __forceinline__ void acc8(float* c, uint4 u) {
  c[0] += __uint_as_float(u.x << 16);
  c[1] += __uint_as_float(u.x & 0xffff0000u);
  c[2] += __uint_as_float(u.y << 16);
  c[3] += __uint_as_float(u.y & 0xffff0000u);
  c[4] += __uint_as_float(u.z << 16);
  c[5] += __uint_as_float(u.z & 0xffff0000u);
  c[6] += __uint_as_float(u.w << 16);
  c[7] += __uint_as_float(u.w & 0xffff0000u);
}

__global__ __launch_bounds__(256) void k_gather(const bf16* __restrict__ xb,
                                                const int* __restrict__ off,
                                                const int* __restrict__ csr,
                                                bf16* __restrict__ aggr, int n) {
  int node = blockIdx.x * 4 + (threadIdx.x >> 6);
  if (node >= n) return;
  int lane = threadIdx.x & 63;
  int s0 = off[node], s1 = off[node + 1];
  float c[8] = {0.f, 0.f, 0.f, 0.f, 0.f, 0.f, 0.f, 0.f};
  int j = s0;
  for (; j + 7 < s1; j += 8) {
    int i0 = csr[j], i1 = csr[j + 1], i2 = csr[j + 2], i3 = csr[j + 3];
    int i4 = csr[j + 4], i5 = csr[j + 5], i6 = csr[j + 6], i7 = csr[j + 7];
    uint4 u0 = *((const uint4*)(xb + (size_t)i0 * D) + lane);
    uint4 u1 = *((const uint4*)(xb + (size_t)i1 * D) + lane);
    uint4 u2 = *((const uint4*)(xb + (size_t)i2 * D) + lane);
    uint4 u3 = *((const uint4*)(xb + (size_t)i3 * D) + lane);
    uint4 u4 = *((const uint4*)(xb + (size_t)i4 * D) + lane);
    uint4 u5 = *((const uint4*)(xb + (size_t)i5 * D) + lane);
    uint4 u6 = *((const uint4*)(xb + (size_t)i6 * D) + lane);
    uint4 u7 = *((const uint4*)(xb + (size_t)i7 * D) + lane);
    acc8(c, u0); acc8(c, u1); acc8(c, u2); acc8(c, u3);
    acc8(c, u4); acc8(c, u5); acc8(c, u6); acc8(c, u7);
  }
  for (; j + 3 < s1; j += 4) {
    int i0 = csr[j], i1 = csr[j + 1], i2 = csr[j + 2], i3 = csr[j + 3];
    uint4 u0 = *((const uint4*)(xb + (size_t)i0 * D) + lane);
    uint4 u1 = *((const uint4*)(xb + (size_t)i1 * D) + lane);
    uint4 u2 = *((const uint4*)(xb + (size_t)i2 * D) + lane);
    uint4 u3 = *((const uint4*)(xb + (size_t)i3 * D) + lane);
    acc8(c, u0); acc8(c, u1); acc8(c, u2); acc8(c, u3);
  }
  for (; j < s1; ++j) {
    int a = csr[j];
    uint4 u = *((const uint4*)(xb + (size_t)a * D) + lane);
    acc8(c, u);
  }
  float rinv = (s1 > s0) ? 1.0f / (float)(s1 - s0) : 0.0f;
  bf16x8 out = { (bf16)(c[0] * rinv), (bf16)(c[1] * rinv), (bf16)(c[2] * rinv), (bf16)(c[3] * rinv),
                 (bf16)(c[4] * rinv), (bf16)(c[5] * rinv), (bf16)(c[6] * rinv), (bf16)(c[7] * rinv) };
  *(bf16x8*)&aggr[(size_t)node * D + lane * 8] = out;
}

// ---------------- (32*MREP)x256 BK=64 double-buffered 2-phase GEMM (known-good) ----------------
__device__ __forceinline__ void gl_lds16(const bf16* g, bf16* l) {
  __builtin_amdgcn_global_load_lds((const __attribute__((address_space(1))) unsigned int*)g,
                                   (__attribute__((address_space(3))) unsigned int*)l, 16, 0, 0);
}

template <int MREP, bool HB>
__global__ __launch_bounds__(512, 2) void k_gemm(const bf16* __restrict__ Xb,
                                                 const bf16* __restrict__ Aggr,
                                                 const bf16* __restrict__ Wc,
                                                 const float* __restrict__ bias,
                                                 bf16* __restrict__ Hb,
                                                 float* __restrict__ Cf,
                                                 float* __restrict__ stat,
                                                 int Mbase, int M) {
  __shared__ __align__(16) bf16 sA0[32 * MREP * 64];
  __shared__ __align__(16) bf16 sB0[256 * 64];
  __shared__ __align__(16) bf16 sA1[32 * MREP * 64];
  __shared__ __align__(16) bf16 sB1[256 * 64];
  const int tid = threadIdx.x;
  const int lane = tid & 63;
  const int wid = tid >> 6;   // 0..7
  const int wm = wid >> 2;    // 0..1 -> row offset wm*(16*MREP)
  const int wn = wid & 3;     // 0..3 -> col offset wn*64
  const int fr = lane & 15;
  const int fq = lane >> 4;

  const int bx = blockIdx.x >> 1;  // M block
  const int by = blockIdx.x & 1;   // N block (siblings adjacent -> A shared in L2/L3)
  const size_t rowA0 = (size_t)Mbase + (size_t)bx * (32 * MREP);
  const int rowB0 = by * 256;

  // Source PRE-SWIZZLED staging (involution with the read-side XOR; conflict-free ds_reads).
  const int lrow = tid >> 3;                         // 0..63
  const int scol = (((tid & 7) ^ (lrow & 7)) * 8);   // swizzled source element offset
  const bf16* pA_x = Xb + (rowA0 + lrow) * D + scol;
  const bf16* pA_g = Aggr + (rowA0 + lrow) * D + scol;
  const bf16* pB = Wc + (size_t)(rowB0 + lrow) * K_TOT + scol;
  bf16* ldsA0 = &sA0[lrow * 64 + (tid & 7) * 8];
  bf16* ldsB0 = &sB0[lrow * 64 + (tid & 7) * 8];
  bf16* ldsA1 = &sA1[lrow * 64 + (tid & 7) * 8];
  bf16* ldsB1 = &sB1[lrow * 64 + (tid & 7) * 8];

  f32x4 acc[MREP][4] = {};

#define STAGE(t, la, lb) do {                                                   \
    const bf16* As = ((t) < 8) ? pA_x : pA_g;                                   \
    const int ko = ((t) & 7) * 64;                                              \
    _Pragma("unroll")                                                           \
    for (int i = 0; i < MREP / 2; ++i)                                          \
      gl_lds16(As + (size_t)i * 64 * D + ko, (la) + i * 64 * 64);               \
    _Pragma("unroll")                                                           \
    for (int i = 0; i < 4; ++i)                                                 \
      gl_lds16(pB + (size_t)i * 64 * K_TOT + (t) * 64, (lb) + i * 64 * 64);     \
  } while (0)

#define COMPUTE(sa, sb) do {                                                    \
    _Pragma("unroll")                                                           \
    for (int kk = 0; kk < 2; ++kk) {                                            \
      const int cx = ((kk * 4 + fq) ^ (fr & 7)) * 8;                            \
      bf16x8 aF[MREP], bF[4];                                                   \
      _Pragma("unroll")                                                         \
      for (int m = 0; m < MREP; ++m)                                            \
        aF[m] = *(const bf16x8*)&(sa)[(wm * (16 * MREP) + m * 16 + fr) * 64 + cx]; \
      _Pragma("unroll")                                                         \
      for (int nn = 0; nn < 4; ++nn)                                            \
        bF[nn] = *(const bf16x8*)&(sb)[(wn * 64 + nn * 16 + fr) * 64 + cx];     \
      _Pragma("unroll")                                                         \
      for (int m = 0; m < MREP; ++m)                                            \
        _Pragma("unroll")                                                       \
        for (int nn = 0; nn < 4; ++nn)                                          \
          acc[m][nn] = __builtin_amdgcn_mfma_f32_16x16x32_bf16(aF[m], bF[nn], acc[m][nn], 0, 0, 0); \
    }                                                                           \
  } while (0)

  STAGE(0, ldsA0, ldsB0);
  __syncthreads();
#pragma unroll 1
  for (int t = 0; t < 16; t += 2) {
    STAGE(t + 1, ldsA1, ldsB1);
    COMPUTE(sA0, sB0);
    __syncthreads();
    if (t + 2 < 16) STAGE(t + 2, ldsA0, ldsB0);
    COMPUTE(sA1, sB1);
    __syncthreads();
  }
#undef STAGE
#undef COMPUTE

  // epilogue: bias, store h (bf16 or f32), fused column stats (skip pad rows)
  const int rowb = (int)rowA0 + wm * (16 * MREP);
  const int colb = rowB0 + wn * 64;
  float s[4] = {0.f, 0.f, 0.f, 0.f}, q[4] = {0.f, 0.f, 0.f, 0.f};
#pragma unroll
  for (int nn = 0; nn < 4; ++nn) {
    int col = colb + nn * 16 + fr;
    float bv = bias[col];
#pragma unroll
    for (int m = 0; m < MREP; ++m) {
      int row0 = rowb + m * 16 + fq * 4;
#pragma unroll
      for (int r = 0; r < 4; ++r) {
        int row = row0 + r;
        if (row < M) {
          float v = acc[m][nn][r] + bv;
          if (HB) Hb[(size_t)row * D + col] = (bf16)v;
          else    Cf[(size_t)row * D + col] = v;
          s[nn] += v;
          q[nn] += v * v;
        }
      }
    }
  }
#pragma unroll
  for (int nn = 0; nn < 4; ++nn) {
    float sv = s[nn], qv = q[nn];
    sv += __shfl_down(sv, 32); sv += __shfl_down(sv, 16);
    qv += __shfl_down(qv, 32); qv += __shfl_down(qv, 16);
    if (lane < 16) {
      int col = colb + nn * 16 + fr;
      atomicAdd(&stat[col], sv);
      atomicAdd(&stat[D + col], qv);
    }
  }
}

// ---------------- normalize + ReLU, finalize folded in; NT stores (out never re-read) ----------------
template <bool HB>
__global__ void k_apply(const bf16* __restrict__ hb, const float* __restrict__ hf,
                        const float* __restrict__ stat, const float* __restrict__ gamma,
                        const float* __restrict__ beta, float* __restrict__ out,
                        int n, float invn) {
  size_t i = (size_t)blockIdx.x * blockDim.x + threadIdx.x;
  size_t stride = (size_t)gridDim.x * blockDim.x;
  size_t total = (size_t)n * (D / 4);
  f32x4* ov = (f32x4*)out;
  for (; i < total; i += stride) {
    int c4 = ((int)i & 127) * 4;
    float vx, vy, vz, vw;
    if (HB) {
      bf16x4 hv = *(const bf16x4*)&hb[i * 4];
      vx = (float)hv[0]; vy = (float)hv[1]; vz = (float)hv[2]; vw = (float)hv[3];
    } else {
      f32x4 v = ((const f32x4*)hf)[i];
      vx = v[0]; vy = v[1]; vz = v[2]; vw = v[3];
    }
    float4 st = *(const float4*)&stat[c4];
    float4 sq = *(const float4*)&stat[D + c4];
    float4 gm = *(const float4*)&gamma[c4];
    float4 bt = *(const float4*)&beta[c4];
    f32x4 o;
    {
      float mu = st.x * invn, var = sq.x * invn - mu * mu;
      float sc = gm.x * rsqrtf(var + EPS);
      o[0] = fmaxf(vx * sc + (bt.x - mu * sc), 0.f);
    }
    {
      float mu = st.y * invn, var = sq.y * invn - mu * mu;
      float sc = gm.y * rsqrtf(var + EPS);
      o[1] = fmaxf(vy * sc + (bt.y - mu * sc), 0.f);
    }
    {
      float mu = st.z * invn, var = sq.z * invn - mu * mu;
      float sc = gm.z * rsqrtf(var + EPS);
      o[2] = fmaxf(vz * sc + (bt.z - mu * sc), 0.f);
    }
    {
      float mu = st.w * invn, var = sq.w * invn - mu * mu;
      float sc = gm.w * rsqrtf(var + EPS);
      o[3] = fmaxf(vw * sc + (bt.w - mu * sc), 0.f);
    }
    __builtin_nontemporal_store(o, ov + i);
  }
}

extern "C" void kernel_launch(void* const* d_in, const int* in_sizes, int n_in,
                              void* d_out, int out_size, void* d_ws, size_t ws_size,
                              hipStream_t stream) {
  const float* x = (const float*)d_in[0];
  const int* ei = (const int*)d_in[1];
  const float* Wl = (const float*)d_in[2];
  const float* bl = (const float*)d_in[3];
  const float* Wr = (const float*)d_in[4];
  const float* gamma = (const float*)d_in[5];
  const float* beta = (const float*)d_in[6];
  float* out = (float*)d_out;

  const int E = in_sizes[1] / 2;
  const int n = in_sizes[0] / D;  // 100000
  const int Mpad = ((n + 255) / 256) * 256;  // 100096 = 391*256
  const int nb = (n + CHUNK - 1) / CHUNK;    // 98

  char* ws = (char*)d_ws;
  size_t off_b = 0;
  bf16* Xb   = (bf16*)(ws + off_b); off_b += (size_t)Mpad * D * sizeof(bf16);
  bf16* Aggr = (bf16*)(ws + off_b); off_b += (size_t)Mpad * D * sizeof(bf16);
  bf16* Wc   = (bf16*)(ws + off_b); off_b += (size_t)D * K_TOT * sizeof(bf16);
  int* cnt   = (int*)(ws + off_b);  off_b += (size_t)n * sizeof(int);
  int* offs  = (int*)(ws + off_b);  off_b += (size_t)(n + 1) * sizeof(int);
  int* cur   = (int*)(ws + off_b);  off_b += (size_t)n * sizeof(int);
  int* csr   = (int*)(ws + off_b);  off_b += (size_t)E * sizeof(int);
  int* bsum  = (int*)(ws + off_b);  off_b += 512 * sizeof(int);
  int* bbase = (int*)(ws + off_b);  off_b += 512 * sizeof(int);
  float* stat = (float*)(ws + off_b); off_b += 2 * D * sizeof(float);
  bf16* Hb   = (bf16*)(ws + off_b);
  const size_t need_hb = off_b + (size_t)Mpad * D * sizeof(bf16);
  const bool use_hb = (ws_size >= need_hb);

  const int* srcIdx = ei;
  const int* dstIdx = ei + E;
  const int padGroups = (Mpad - n) * D / 8;
  const float invn = 1.0f / (float)n;

  // Exact-round partition: 384 M-blocks -> 768 tiles = 3 full occupancy rounds;
  // remaining 7 M-blocks as 14 half-height tiles in one short tail launch.
  const int mb256 = Mpad / 256;                 // 391
  int mainMB = (mb256 / 128) * 128;             // 384
  if (mainMB == 0) mainMB = mb256;
  const int tailMB = (Mpad - mainMB * 256) / 128;  // 14
  const int Mbase2 = mainMB * 256;

  k_prep<<<2048, 256, 0, stream>>>(x, Xb, stat,
                                   Xb + (size_t)n * D, Aggr + (size_t)n * D,
                                   Wl, Wr, Wc,
                                   padGroups, (size_t)n * D / 8);

  // cooperative merged CSR builder (replaces degree/blocksum/scanb/offsets/fill)
  {
    const int* srcA = srcIdx;
    const int* dstA = dstIdx;
    int nA = n, EA = E, nbA = nb;
    void* args[] = { (void*)&srcA, (void*)&dstA, (void*)&cnt, (void*)&cur,
                     (void*)&offs, (void*)&csr, (void*)&bsum, (void*)&bbase,
                     (void*)&nA, (void*)&EA, (void*)&nbA };
    hipLaunchCooperativeKernel((const void*)k_csr, dim3(256), dim3(256), args, 0, stream);
  }

  k_gather<<<(n + 3) / 4, 256, 0, stream>>>(Xb, offs, csr, Aggr, n);
  if (use_hb) {
    k_gemm<8, true><<<mainMB * 2, 512, 0, stream>>>(Xb, Aggr, Wc, bl, Hb, out, stat, 0, n);
    if (tailMB)
      k_gemm<4, true><<<tailMB * 2, 512, 0, stream>>>(Xb, Aggr, Wc, bl, Hb, out, stat, Mbase2, n);
    k_apply<true><<<2048, 256, 0, stream>>>(Hb, out, stat, gamma, beta, out, n, invn);
  } else {
    k_gemm<8, false><<<mainMB * 2, 512, 0, stream>>>(Xb, Aggr, Wc, bl, Hb, out, stat, 0, n);
    if (tailMB)
      k_gemm<4, false><<<tailMB * 2, 512, 0, stream>>>(Xb, Aggr, Wc, bl, Hb, out, stat, Mbase2, n);
    k_apply<false><<<2048, 256, 0, stream>>>(Hb, out, stat, gamma, beta, out, n, invn);
  }
}

// Round 14
// 533.233 us; speedup vs baseline: 1.2271x; 1.2271x over previous
//
#include <hip/hip_runtime.h>
#include <stdint.h>

#define D 512
#define K_TOT 1024
#define EPS 1e-5f
#define CHUNK 1024

typedef __bf16 bf16;
typedef bf16 bf16x4 __attribute__((ext_vector_type(4)));
typedef bf16 bf16x8 __attribute__((ext_vector_type(8)));
typedef float f32x4 __attribute__((ext_vector_type(4)));

// ---------------- prep: convert x->bf16 (NT loads), zero cnt/cur/stat/pads, build Wc ----------------
__global__ void k_prep(const float* __restrict__ x, bf16* __restrict__ xb,
                       int* __restrict__ cnt, int* __restrict__ cur, float* __restrict__ stat,
                       bf16* __restrict__ padX, bf16* __restrict__ padA,
                       const float* __restrict__ Wl, const float* __restrict__ Wr,
                       bf16* __restrict__ Wc,
                       int n, int padGroups, size_t total8) {
  int gid = blockIdx.x * blockDim.x + threadIdx.x;
  int stride = gridDim.x * blockDim.x;
  if (gid < n) { cnt[gid] = 0; cur[gid] = 0; }
  if (gid < 2 * D) stat[gid] = 0.f;
  if (gid < padGroups) {
    bf16x8 z = {};
    *(bf16x8*)&padX[(size_t)gid * 8] = z;
    *(bf16x8*)&padA[(size_t)gid * 8] = z;
  }
  // build Wcat[o][k] = k<512 ? W_r[o][k] : W_l[o][k-512]
  for (int w = gid; w < D * K_TOT; w += stride) {
    int o = w >> 10, k = w & 1023;
    float v = (k < D) ? Wr[o * D + k] : Wl[o * D + (k - D)];
    Wc[w] = (bf16)v;
  }
  // x (f32, read-once) -> Xb (bf16): nontemporal loads keep the 205MB stream
  // from evicting the bf16 working set (Xb/csr) out of L3 before k_gather.
  size_t i = (size_t)gid;
  size_t sstride = (size_t)stride;
  const f32x4* xv = (const f32x4*)x;
  for (; i < total8; i += sstride) {
    f32x4 a = __builtin_nontemporal_load(xv + i * 2);
    f32x4 b = __builtin_nontemporal_load(xv + i * 2 + 1);
    bf16x8 v = { (bf16)a[0], (bf16)a[1], (bf16)a[2], (bf16)a[3],
                 (bf16)b[0], (bf16)b[1], (bf16)b[2], (bf16)b[3] };
    *(bf16x8*)&xb[i * 8] = v;
  }
}

// ---------------- degree count ----------------
__global__ void k_degree(const int* __restrict__ dst, int* __restrict__ cnt, int E) {
  int i = blockIdx.x * blockDim.x + threadIdx.x;
  int stride = gridDim.x * blockDim.x;
  for (; i < E; i += stride) atomicAdd(&cnt[dst[i]], 1);
}

// ---------------- scan step 1: per-chunk sums ----------------
__global__ void k_blocksum(const int* __restrict__ cnt, int* __restrict__ bsum, int n) {
  __shared__ int red[4];
  int b = blockIdx.x;
  int base = b * CHUNK;
  int s = 0;
  for (int i = threadIdx.x; i < CHUNK; i += 256) {
    int idx = base + i;
    s += (idx < n) ? cnt[idx] : 0;
  }
#pragma unroll
  for (int o = 32; o > 0; o >>= 1) s += __shfl_down(s, o);
  if ((threadIdx.x & 63) == 0) red[threadIdx.x >> 6] = s;
  __syncthreads();
  if (threadIdx.x == 0) bsum[b] = red[0] + red[1] + red[2] + red[3];
}

// ---------------- scan step 2: serial scan of chunk sums ----------------
__global__ void k_scanb(int* __restrict__ bsum, int* __restrict__ bbase, int nb,
                        int* __restrict__ off, int n, int E) {
  if (threadIdx.x == 0) {
    int run = 0;
    for (int i = 0; i < nb; ++i) { bbase[i] = run; run += bsum[i]; }
    off[n] = E;
  }
}

// ---------------- scan step 3: per-chunk exclusive scan + base ----------------
__global__ void k_offsets(const int* __restrict__ cnt, const int* __restrict__ bbase,
                          int* __restrict__ off, int n) {
  __shared__ int tsum[256];
  int b = blockIdx.x;
  int i0 = b * CHUNK + threadIdx.x * 4;
  int vals[4];
  int s = 0;
#pragma unroll
  for (int j = 0; j < 4; ++j) {
    int idx = i0 + j;
    vals[j] = (idx < n) ? cnt[idx] : 0;
    s += vals[j];
  }
  tsum[threadIdx.x] = s;
  __syncthreads();
  for (int d = 1; d < 256; d <<= 1) {
    int v = (threadIdx.x >= d) ? tsum[threadIdx.x - d] : 0;
    __syncthreads();
    tsum[threadIdx.x] += v;
    __syncthreads();
  }
  int excl = tsum[threadIdx.x] - s + bbase[b];
#pragma unroll
  for (int j = 0; j < 4; ++j) {
    int idx = i0 + j;
    if (idx < n) off[idx] = excl;
    excl += vals[j];
  }
}

// ---------------- CSR fill ----------------
__global__ void k_fill(const int* __restrict__ src, const int* __restrict__ dst,
                       const int* __restrict__ off, int* __restrict__ cur,
                       int* __restrict__ csr, int E) {
  int i = blockIdx.x * blockDim.x + threadIdx.x;
  int stride = gridDim.x * blockDim.x;
  for (; i < E; i += stride) {
    int d = dst[i];
    int pos = off[d] + atomicAdd(&cur[d], 1);
    csr[pos] = src[i];
  }
}

// ---------------- gather (bf16 rows): Aggr[node] = mean of Xb[src], one wave/node ----------------
__device__ __forceinline__ void acc8(float* c, uint4 u) {
  c[0] += __uint_as_float(u.x << 16);
  c[1] += __uint_as_float(u.x & 0xffff0000u);
  c[2] += __uint_as_float(u.y << 16);
  c[3] += __uint_as_float(u.y & 0xffff0000u);
  c[4] += __uint_as_float(u.z << 16);
  c[5] += __uint_as_float(u.z & 0xffff0000u);
  c[6] += __uint_as_float(u.w << 16);
  c[7] += __uint_as_float(u.w & 0xffff0000u);
}

__global__ __launch_bounds__(256) void k_gather(const bf16* __restrict__ xb,
                                                const int* __restrict__ off,
                                                const int* __restrict__ csr,
                                                bf16* __restrict__ aggr, int n) {
  int node = blockIdx.x * 4 + (threadIdx.x >> 6);
  if (node >= n) return;
  int lane = threadIdx.x & 63;
  int s0 = off[node], s1 = off[node + 1];
  float c[8] = {0.f, 0.f, 0.f, 0.f, 0.f, 0.f, 0.f, 0.f};
  int j = s0;
  for (; j + 7 < s1; j += 8) {
    int i0 = csr[j], i1 = csr[j + 1], i2 = csr[j + 2], i3 = csr[j + 3];
    int i4 = csr[j + 4], i5 = csr[j + 5], i6 = csr[j + 6], i7 = csr[j + 7];
    uint4 u0 = *((const uint4*)(xb + (size_t)i0 * D) + lane);
    uint4 u1 = *((const uint4*)(xb + (size_t)i1 * D) + lane);
    uint4 u2 = *((const uint4*)(xb + (size_t)i2 * D) + lane);
    uint4 u3 = *((const uint4*)(xb + (size_t)i3 * D) + lane);
    uint4 u4 = *((const uint4*)(xb + (size_t)i4 * D) + lane);
    uint4 u5 = *((const uint4*)(xb + (size_t)i5 * D) + lane);
    uint4 u6 = *((const uint4*)(xb + (size_t)i6 * D) + lane);
    uint4 u7 = *((const uint4*)(xb + (size_t)i7 * D) + lane);
    acc8(c, u0); acc8(c, u1); acc8(c, u2); acc8(c, u3);
    acc8(c, u4); acc8(c, u5); acc8(c, u6); acc8(c, u7);
  }
  for (; j + 3 < s1; j += 4) {
    int i0 = csr[j], i1 = csr[j + 1], i2 = csr[j + 2], i3 = csr[j + 3];
    uint4 u0 = *((const uint4*)(xb + (size_t)i0 * D) + lane);
    uint4 u1 = *((const uint4*)(xb + (size_t)i1 * D) + lane);
    uint4 u2 = *((const uint4*)(xb + (size_t)i2 * D) + lane);
    uint4 u3 = *((const uint4*)(xb + (size_t)i3 * D) + lane);
    acc8(c, u0); acc8(c, u1); acc8(c, u2); acc8(c, u3);
  }
  for (; j < s1; ++j) {
    int a = csr[j];
    uint4 u = *((const uint4*)(xb + (size_t)a * D) + lane);
    acc8(c, u);
  }
  float rinv = (s1 > s0) ? 1.0f / (float)(s1 - s0) : 0.0f;
  bf16x8 out = { (bf16)(c[0] * rinv), (bf16)(c[1] * rinv), (bf16)(c[2] * rinv), (bf16)(c[3] * rinv),
                 (bf16)(c[4] * rinv), (bf16)(c[5] * rinv), (bf16)(c[6] * rinv), (bf16)(c[7] * rinv) };
  *(bf16x8*)&aggr[(size_t)node * D + lane * 8] = out;
}

// ---------------- (32*MREP)x256 BK=64 double-buffered 2-phase GEMM (known-good) ----------------
__device__ __forceinline__ void gl_lds16(const bf16* g, bf16* l) {
  __builtin_amdgcn_global_load_lds((const __attribute__((address_space(1))) unsigned int*)g,
                                   (__attribute__((address_space(3))) unsigned int*)l, 16, 0, 0);
}

template <int MREP, bool HB>
__global__ __launch_bounds__(512, 2) void k_gemm(const bf16* __restrict__ Xb,
                                                 const bf16* __restrict__ Aggr,
                                                 const bf16* __restrict__ Wc,
                                                 const float* __restrict__ bias,
                                                 bf16* __restrict__ Hb,
                                                 float* __restrict__ Cf,
                                                 float* __restrict__ stat,
                                                 int Mbase, int M) {
  __shared__ __align__(16) bf16 sA0[32 * MREP * 64];
  __shared__ __align__(16) bf16 sB0[256 * 64];
  __shared__ __align__(16) bf16 sA1[32 * MREP * 64];
  __shared__ __align__(16) bf16 sB1[256 * 64];
  const int tid = threadIdx.x;
  const int lane = tid & 63;
  const int wid = tid >> 6;   // 0..7
  const int wm = wid >> 2;    // 0..1 -> row offset wm*(16*MREP)
  const int wn = wid & 3;     // 0..3 -> col offset wn*64
  const int fr = lane & 15;
  const int fq = lane >> 4;

  const int bx = blockIdx.x >> 1;  // M block
  const int by = blockIdx.x & 1;   // N block (siblings adjacent -> A shared in L2/L3)
  const size_t rowA0 = (size_t)Mbase + (size_t)bx * (32 * MREP);
  const int rowB0 = by * 256;

  // Source PRE-SWIZZLED staging (involution with the read-side XOR; conflict-free ds_reads).
  const int lrow = tid >> 3;                         // 0..63
  const int scol = (((tid & 7) ^ (lrow & 7)) * 8);   // swizzled source element offset
  const bf16* pA_x = Xb + (rowA0 + lrow) * D + scol;
  const bf16* pA_g = Aggr + (rowA0 + lrow) * D + scol;
  const bf16* pB = Wc + (size_t)(rowB0 + lrow) * K_TOT + scol;
  bf16* ldsA0 = &sA0[lrow * 64 + (tid & 7) * 8];
  bf16* ldsB0 = &sB0[lrow * 64 + (tid & 7) * 8];
  bf16* ldsA1 = &sA1[lrow * 64 + (tid & 7) * 8];
  bf16* ldsB1 = &sB1[lrow * 64 + (tid & 7) * 8];

  f32x4 acc[MREP][4] = {};

#define STAGE(t, la, lb) do {                                                   \
    const bf16* As = ((t) < 8) ? pA_x : pA_g;                                   \
    const int ko = ((t) & 7) * 64;                                              \
    _Pragma("unroll")                                                           \
    for (int i = 0; i < MREP / 2; ++i)                                          \
      gl_lds16(As + (size_t)i * 64 * D + ko, (la) + i * 64 * 64);               \
    _Pragma("unroll")                                                           \
    for (int i = 0; i < 4; ++i)                                                 \
      gl_lds16(pB + (size_t)i * 64 * K_TOT + (t) * 64, (lb) + i * 64 * 64);     \
  } while (0)

#define COMPUTE(sa, sb) do {                                                    \
    _Pragma("unroll")                                                           \
    for (int kk = 0; kk < 2; ++kk) {                                            \
      const int cx = ((kk * 4 + fq) ^ (fr & 7)) * 8;                            \
      bf16x8 aF[MREP], bF[4];                                                   \
      _Pragma("unroll")                                                         \
      for (int m = 0; m < MREP; ++m)                                            \
        aF[m] = *(const bf16x8*)&(sa)[(wm * (16 * MREP) + m * 16 + fr) * 64 + cx]; \
      _Pragma("unroll")                                                         \
      for (int nn = 0; nn < 4; ++nn)                                            \
        bF[nn] = *(const bf16x8*)&(sb)[(wn * 64 + nn * 16 + fr) * 64 + cx];     \
      _Pragma("unroll")                                                         \
      for (int m = 0; m < MREP; ++m)                                            \
        _Pragma("unroll")                                                       \
        for (int nn = 0; nn < 4; ++nn)                                          \
          acc[m][nn] = __builtin_amdgcn_mfma_f32_16x16x32_bf16(aF[m], bF[nn], acc[m][nn], 0, 0, 0); \
    }                                                                           \
  } while (0)

  STAGE(0, ldsA0, ldsB0);
  __syncthreads();
#pragma unroll 1
  for (int t = 0; t < 16; t += 2) {
    STAGE(t + 1, ldsA1, ldsB1);
    COMPUTE(sA0, sB0);
    __syncthreads();
    if (t + 2 < 16) STAGE(t + 2, ldsA0, ldsB0);
    COMPUTE(sA1, sB1);
    __syncthreads();
  }
#undef STAGE
#undef COMPUTE

  // epilogue: bias, store h (bf16 or f32), fused column stats (skip pad rows)
  const int rowb = (int)rowA0 + wm * (16 * MREP);
  const int colb = rowB0 + wn * 64;
  float s[4] = {0.f, 0.f, 0.f, 0.f}, q[4] = {0.f, 0.f, 0.f, 0.f};
#pragma unroll
  for (int nn = 0; nn < 4; ++nn) {
    int col = colb + nn * 16 + fr;
    float bv = bias[col];
#pragma unroll
    for (int m = 0; m < MREP; ++m) {
      int row0 = rowb + m * 16 + fq * 4;
#pragma unroll
      for (int r = 0; r < 4; ++r) {
        int row = row0 + r;
        if (row < M) {
          float v = acc[m][nn][r] + bv;
          if (HB) Hb[(size_t)row * D + col] = (bf16)v;
          else    Cf[(size_t)row * D + col] = v;
          s[nn] += v;
          q[nn] += v * v;
        }
      }
    }
  }
#pragma unroll
  for (int nn = 0; nn < 4; ++nn) {
    float sv = s[nn], qv = q[nn];
    sv += __shfl_down(sv, 32); sv += __shfl_down(sv, 16);
    qv += __shfl_down(qv, 32); qv += __shfl_down(qv, 16);
    if (lane < 16) {
      int col = colb + nn * 16 + fr;
      atomicAdd(&stat[col], sv);
      atomicAdd(&stat[D + col], qv);
    }
  }
}

// ---------------- normalize + ReLU, finalize folded in; NT stores (out never re-read) ----------------
template <bool HB>
__global__ void k_apply(const bf16* __restrict__ hb, const float* __restrict__ hf,
                        const float* __restrict__ stat, const float* __restrict__ gamma,
                        const float* __restrict__ beta, float* __restrict__ out,
                        int n, float invn) {
  size_t i = (size_t)blockIdx.x * blockDim.x + threadIdx.x;
  size_t stride = (size_t)gridDim.x * blockDim.x;
  size_t total = (size_t)n * (D / 4);
  f32x4* ov = (f32x4*)out;
  for (; i < total; i += stride) {
    int c4 = ((int)i & 127) * 4;
    float vx, vy, vz, vw;
    if (HB) {
      bf16x4 hv = *(const bf16x4*)&hb[i * 4];
      vx = (float)hv[0]; vy = (float)hv[1]; vz = (float)hv[2]; vw = (float)hv[3];
    } else {
      f32x4 v = ((const f32x4*)hf)[i];
      vx = v[0]; vy = v[1]; vz = v[2]; vw = v[3];
    }
    float4 st = *(const float4*)&stat[c4];
    float4 sq = *(const float4*)&stat[D + c4];
    float4 gm = *(const float4*)&gamma[c4];
    float4 bt = *(const float4*)&beta[c4];
    f32x4 o;
    {
      float mu = st.x * invn, var = sq.x * invn - mu * mu;
      float sc = gm.x * rsqrtf(var + EPS);
      o[0] = fmaxf(vx * sc + (bt.x - mu * sc), 0.f);
    }
    {
      float mu = st.y * invn, var = sq.y * invn - mu * mu;
      float sc = gm.y * rsqrtf(var + EPS);
      o[1] = fmaxf(vy * sc + (bt.y - mu * sc), 0.f);
    }
    {
      float mu = st.z * invn, var = sq.z * invn - mu * mu;
      float sc = gm.z * rsqrtf(var + EPS);
      o[2] = fmaxf(vz * sc + (bt.z - mu * sc), 0.f);
    }
    {
      float mu = st.w * invn, var = sq.w * invn - mu * mu;
      float sc = gm.w * rsqrtf(var + EPS);
      o[3] = fmaxf(vw * sc + (bt.w - mu * sc), 0.f);
    }
    __builtin_nontemporal_store(o, ov + i);
  }
}

extern "C" void kernel_launch(void* const* d_in, const int* in_sizes, int n_in,
                              void* d_out, int out_size, void* d_ws, size_t ws_size,
                              hipStream_t stream) {
  const float* x = (const float*)d_in[0];
  const int* ei = (const int*)d_in[1];
  const float* Wl = (const float*)d_in[2];
  const float* bl = (const float*)d_in[3];
  const float* Wr = (const float*)d_in[4];
  const float* gamma = (const float*)d_in[5];
  const float* beta = (const float*)d_in[6];
  float* out = (float*)d_out;

  const int E = in_sizes[1] / 2;
  const int n = in_sizes[0] / D;  // 100000
  const int Mpad = ((n + 255) / 256) * 256;  // 100096 = 391*256
  const int nb = (n + CHUNK - 1) / CHUNK;    // 98

  char* ws = (char*)d_ws;
  size_t off_b = 0;
  bf16* Xb   = (bf16*)(ws + off_b); off_b += (size_t)Mpad * D * sizeof(bf16);
  bf16* Aggr = (bf16*)(ws + off_b); off_b += (size_t)Mpad * D * sizeof(bf16);
  bf16* Wc   = (bf16*)(ws + off_b); off_b += (size_t)D * K_TOT * sizeof(bf16);
  int* cnt   = (int*)(ws + off_b);  off_b += (size_t)n * sizeof(int);
  int* offs  = (int*)(ws + off_b);  off_b += (size_t)(n + 1) * sizeof(int);
  int* cur   = (int*)(ws + off_b);  off_b += (size_t)n * sizeof(int);
  int* csr   = (int*)(ws + off_b);  off_b += (size_t)E * sizeof(int);
  int* bsum  = (int*)(ws + off_b);  off_b += 512 * sizeof(int);
  int* bbase = (int*)(ws + off_b);  off_b += 512 * sizeof(int);
  float* stat = (float*)(ws + off_b); off_b += 2 * D * sizeof(float);
  bf16* Hb   = (bf16*)(ws + off_b);
  const size_t need_hb = off_b + (size_t)Mpad * D * sizeof(bf16);
  const bool use_hb = (ws_size >= need_hb);

  const int* srcIdx = ei;
  const int* dstIdx = ei + E;
  const int padGroups = (Mpad - n) * D / 8;
  const float invn = 1.0f / (float)n;

  // Exact-round partition: 384 M-blocks -> 768 tiles = 3 full occupancy rounds;
  // remaining 7 M-blocks as 14 half-height tiles in one short tail launch.
  const int mb256 = Mpad / 256;                 // 391
  int mainMB = (mb256 / 128) * 128;             // 384
  if (mainMB == 0) mainMB = mb256;
  const int tailMB = (Mpad - mainMB * 256) / 128;  // 14
  const int Mbase2 = mainMB * 256;

  k_prep<<<2048, 256, 0, stream>>>(x, Xb, cnt, cur, stat,
                                   Xb + (size_t)n * D, Aggr + (size_t)n * D,
                                   Wl, Wr, Wc,
                                   n, padGroups, (size_t)n * D / 8);
  k_degree<<<2048, 256, 0, stream>>>(dstIdx, cnt, E);
  k_blocksum<<<nb, 256, 0, stream>>>(cnt, bsum, n);
  k_scanb<<<1, 64, 0, stream>>>(bsum, bbase, nb, offs, n, E);
  k_offsets<<<nb, 256, 0, stream>>>(cnt, bbase, offs, n);
  k_fill<<<2048, 256, 0, stream>>>(srcIdx, dstIdx, offs, cur, csr, E);
  k_gather<<<(n + 3) / 4, 256, 0, stream>>>(Xb, offs, csr, Aggr, n);
  if (use_hb) {
    k_gemm<8, true><<<mainMB * 2, 512, 0, stream>>>(Xb, Aggr, Wc, bl, Hb, out, stat, 0, n);
    if (tailMB)
      k_gemm<4, true><<<tailMB * 2, 512, 0, stream>>>(Xb, Aggr, Wc, bl, Hb, out, stat, Mbase2, n);
    k_apply<true><<<2048, 256, 0, stream>>>(Hb, out, stat, gamma, beta, out, n, invn);
  } else {
    k_gemm<8, false><<<mainMB * 2, 512, 0, stream>>>(Xb, Aggr, Wc, bl, Hb, out, stat, 0, n);
    if (tailMB)
      k_gemm<4, false><<<tailMB * 2, 512, 0, stream>>>(Xb, Aggr, Wc, bl, Hb, out, stat, Mbase2, n);
    k_apply<false><<<2048, 256, 0, stream>>>(Hb, out, stat, gamma, beta, out, n, invn);
  }
}

// Round 15
// 523.625 us; speedup vs baseline: 1.2497x; 1.0183x over previous
//
#include <hip/hip_runtime.h>
#include <stdint.h>

#define D 512
#define K_TOT 1024
#define EPS 1e-5f
#define CHUNK 1024

typedef __bf16 bf16;
typedef bf16 bf16x4 __attribute__((ext_vector_type(4)));
typedef bf16 bf16x8 __attribute__((ext_vector_type(8)));
typedef float f32x4 __attribute__((ext_vector_type(4)));

// ---------------- prep: convert x->bf16 (NT loads), zero cnt/cur/stat/pads, build Wc ----------------
__global__ void k_prep(const float* __restrict__ x, bf16* __restrict__ xb,
                       int* __restrict__ cnt, int* __restrict__ cur, float* __restrict__ stat,
                       bf16* __restrict__ padX, bf16* __restrict__ padA,
                       const float* __restrict__ Wl, const float* __restrict__ Wr,
                       bf16* __restrict__ Wc,
                       int n, int padGroups, size_t total8) {
  int gid = blockIdx.x * blockDim.x + threadIdx.x;
  int stride = gridDim.x * blockDim.x;
  if (gid < n) { cnt[gid] = 0; cur[gid] = 0; }
  if (gid < 2 * D) stat[gid] = 0.f;
  if (gid < padGroups) {
    bf16x8 z = {};
    *(bf16x8*)&padX[(size_t)gid * 8] = z;
    *(bf16x8*)&padA[(size_t)gid * 8] = z;
  }
  // build Wcat[o][k] = k<512 ? W_r[o][k] : W_l[o][k-512]
  for (int w = gid; w < D * K_TOT; w += stride) {
    int o = w >> 10, k = w & 1023;
    float v = (k < D) ? Wr[o * D + k] : Wl[o * D + (k - D)];
    Wc[w] = (bf16)v;
  }
  // x (f32, read-once) -> Xb (bf16): nontemporal loads keep the 205MB stream
  // from evicting the bf16 working set (Xb/csr) out of L3 before k_gather.
  size_t i = (size_t)gid;
  size_t sstride = (size_t)stride;
  const f32x4* xv = (const f32x4*)x;
  for (; i < total8; i += sstride) {
    f32x4 a = __builtin_nontemporal_load(xv + i * 2);
    f32x4 b = __builtin_nontemporal_load(xv + i * 2 + 1);
    bf16x8 v = { (bf16)a[0], (bf16)a[1], (bf16)a[2], (bf16)a[3],
                 (bf16)b[0], (bf16)b[1], (bf16)b[2], (bf16)b[3] };
    *(bf16x8*)&xb[i * 8] = v;
  }
}

// ---------------- degree count ----------------
__global__ void k_degree(const int* __restrict__ dst, int* __restrict__ cnt, int E) {
  int i = blockIdx.x * blockDim.x + threadIdx.x;
  int stride = gridDim.x * blockDim.x;
  for (; i < E; i += stride) atomicAdd(&cnt[dst[i]], 1);
}

// ---------------- scan step 1: per-chunk sums ----------------
__global__ void k_blocksum(const int* __restrict__ cnt, int* __restrict__ bsum, int n) {
  __shared__ int red[4];
  int b = blockIdx.x;
  int base = b * CHUNK;
  int s = 0;
  for (int i = threadIdx.x; i < CHUNK; i += 256) {
    int idx = base + i;
    s += (idx < n) ? cnt[idx] : 0;
  }
#pragma unroll
  for (int o = 32; o > 0; o >>= 1) s += __shfl_down(s, o);
  if ((threadIdx.x & 63) == 0) red[threadIdx.x >> 6] = s;
  __syncthreads();
  if (threadIdx.x == 0) bsum[b] = red[0] + red[1] + red[2] + red[3];
}

// ---------------- scan step 2: per-chunk exclusive scan; base computed in-block ----------------
// (k_scanb folded in: each block redundantly reduces bsum[0..b), b <= nb-1 < 256.)
__global__ void k_offsets(const int* __restrict__ cnt, const int* __restrict__ bsum,
                          int* __restrict__ off, int n, int E) {
  __shared__ int red[4];
  __shared__ int baseSh;
  __shared__ int tsum[256];
  int b = blockIdx.x;
  // block-wide reduce of bsum[0..b) -> exclusive base for this chunk
  int s0 = ((int)threadIdx.x < b) ? bsum[threadIdx.x] : 0;
#pragma unroll
  for (int o = 32; o > 0; o >>= 1) s0 += __shfl_down(s0, o);
  if ((threadIdx.x & 63) == 0) red[threadIdx.x >> 6] = s0;
  __syncthreads();
  if (threadIdx.x == 0) baseSh = red[0] + red[1] + red[2] + red[3];
  if (b == 0 && threadIdx.x == 0) off[n] = E;
  __syncthreads();
  const int bbase = baseSh;

  int i0 = b * CHUNK + threadIdx.x * 4;
  int vals[4];
  int s = 0;
#pragma unroll
  for (int j = 0; j < 4; ++j) {
    int idx = i0 + j;
    vals[j] = (idx < n) ? cnt[idx] : 0;
    s += vals[j];
  }
  tsum[threadIdx.x] = s;
  __syncthreads();
  for (int d = 1; d < 256; d <<= 1) {
    int v = ((int)threadIdx.x >= d) ? tsum[threadIdx.x - d] : 0;
    __syncthreads();
    tsum[threadIdx.x] += v;
    __syncthreads();
  }
  int excl = tsum[threadIdx.x] - s + bbase;
#pragma unroll
  for (int j = 0; j < 4; ++j) {
    int idx = i0 + j;
    if (idx < n) off[idx] = excl;
    excl += vals[j];
  }
}

// ---------------- CSR fill ----------------
__global__ void k_fill(const int* __restrict__ src, const int* __restrict__ dst,
                       const int* __restrict__ off, int* __restrict__ cur,
                       int* __restrict__ csr, int E) {
  int i = blockIdx.x * blockDim.x + threadIdx.x;
  int stride = gridDim.x * blockDim.x;
  for (; i < E; i += stride) {
    int d = dst[i];
    int pos = off[d] + atomicAdd(&cur[d], 1);
    csr[pos] = src[i];
  }
}

// ---------------- gather (bf16 rows): Aggr[node] = mean of Xb[src], one wave/node ----------------
__device__ __forceinline__ void acc8(float* c, uint4 u) {
  c[0] += __uint_as_float(u.x << 16);
  c[1] += __uint_as_float(u.x & 0xffff0000u);
  c[2] += __uint_as_float(u.y << 16);
  c[3] += __uint_as_float(u.y & 0xffff0000u);
  c[4] += __uint_as_float(u.z << 16);
  c[5] += __uint_as_float(u.z & 0xffff0000u);
  c[6] += __uint_as_float(u.w << 16);
  c[7] += __uint_as_float(u.w & 0xffff0000u);
}

__global__ __launch_bounds__(256) void k_gather(const bf16* __restrict__ xb,
                                                const int* __restrict__ off,
                                                const int* __restrict__ csr,
                                                bf16* __restrict__ aggr, int n) {
  int node = blockIdx.x * 4 + (threadIdx.x >> 6);
  if (node >= n) return;
  int lane = threadIdx.x & 63;
  int s0 = off[node], s1 = off[node + 1];
  float c[8] = {0.f, 0.f, 0.f, 0.f, 0.f, 0.f, 0.f, 0.f};
  int j = s0;
  for (; j + 7 < s1; j += 8) {
    int i0 = csr[j], i1 = csr[j + 1], i2 = csr[j + 2], i3 = csr[j + 3];
    int i4 = csr[j + 4], i5 = csr[j + 5], i6 = csr[j + 6], i7 = csr[j + 7];
    uint4 u0 = *((const uint4*)(xb + (size_t)i0 * D) + lane);
    uint4 u1 = *((const uint4*)(xb + (size_t)i1 * D) + lane);
    uint4 u2 = *((const uint4*)(xb + (size_t)i2 * D) + lane);
    uint4 u3 = *((const uint4*)(xb + (size_t)i3 * D) + lane);
    uint4 u4 = *((const uint4*)(xb + (size_t)i4 * D) + lane);
    uint4 u5 = *((const uint4*)(xb + (size_t)i5 * D) + lane);
    uint4 u6 = *((const uint4*)(xb + (size_t)i6 * D) + lane);
    uint4 u7 = *((const uint4*)(xb + (size_t)i7 * D) + lane);
    acc8(c, u0); acc8(c, u1); acc8(c, u2); acc8(c, u3);
    acc8(c, u4); acc8(c, u5); acc8(c, u6); acc8(c, u7);
  }
  for (; j + 3 < s1; j += 4) {
    int i0 = csr[j], i1 = csr[j + 1], i2 = csr[j + 2], i3 = csr[j + 3];
    uint4 u0 = *((const uint4*)(xb + (size_t)i0 * D) + lane);
    uint4 u1 = *((const uint4*)(xb + (size_t)i1 * D) + lane);
    uint4 u2 = *((const uint4*)(xb + (size_t)i2 * D) + lane);
    uint4 u3 = *((const uint4*)(xb + (size_t)i3 * D) + lane);
    acc8(c, u0); acc8(c, u1); acc8(c, u2); acc8(c, u3);
  }
  for (; j < s1; ++j) {
    int a = csr[j];
    uint4 u = *((const uint4*)(xb + (size_t)a * D) + lane);
    acc8(c, u);
  }
  float rinv = (s1 > s0) ? 1.0f / (float)(s1 - s0) : 0.0f;
  bf16x8 out = { (bf16)(c[0] * rinv), (bf16)(c[1] * rinv), (bf16)(c[2] * rinv), (bf16)(c[3] * rinv),
                 (bf16)(c[4] * rinv), (bf16)(c[5] * rinv), (bf16)(c[6] * rinv), (bf16)(c[7] * rinv) };
  *(bf16x8*)&aggr[(size_t)node * D + lane * 8] = out;
}

// ---------------- (32*MREP)x256 BK=64 double-buffered 2-phase GEMM (known-good) ----------------
__device__ __forceinline__ void gl_lds16(const bf16* g, bf16* l) {
  __builtin_amdgcn_global_load_lds((const __attribute__((address_space(1))) unsigned int*)g,
                                   (__attribute__((address_space(3))) unsigned int*)l, 16, 0, 0);
}

template <int MREP, bool HB>
__global__ __launch_bounds__(512, 2) void k_gemm(const bf16* __restrict__ Xb,
                                                 const bf16* __restrict__ Aggr,
                                                 const bf16* __restrict__ Wc,
                                                 const float* __restrict__ bias,
                                                 bf16* __restrict__ Hb,
                                                 float* __restrict__ Cf,
                                                 float* __restrict__ stat,
                                                 int Mbase, int M) {
  __shared__ __align__(16) bf16 sA0[32 * MREP * 64];
  __shared__ __align__(16) bf16 sB0[256 * 64];
  __shared__ __align__(16) bf16 sA1[32 * MREP * 64];
  __shared__ __align__(16) bf16 sB1[256 * 64];
  const int tid = threadIdx.x;
  const int lane = tid & 63;
  const int wid = tid >> 6;   // 0..7
  const int wm = wid >> 2;    // 0..1 -> row offset wm*(16*MREP)
  const int wn = wid & 3;     // 0..3 -> col offset wn*64
  const int fr = lane & 15;
  const int fq = lane >> 4;

  const int bx = blockIdx.x >> 1;  // M block
  const int by = blockIdx.x & 1;   // N block (siblings adjacent -> A shared in L2/L3)
  const size_t rowA0 = (size_t)Mbase + (size_t)bx * (32 * MREP);
  const int rowB0 = by * 256;

  // Source PRE-SWIZZLED staging (involution with the read-side XOR; conflict-free ds_reads).
  const int lrow = tid >> 3;                         // 0..63
  const int scol = (((tid & 7) ^ (lrow & 7)) * 8);   // swizzled source element offset
  const bf16* pA_x = Xb + (rowA0 + lrow) * D + scol;
  const bf16* pA_g = Aggr + (rowA0 + lrow) * D + scol;
  const bf16* pB = Wc + (size_t)(rowB0 + lrow) * K_TOT + scol;
  bf16* ldsA0 = &sA0[lrow * 64 + (tid & 7) * 8];
  bf16* ldsB0 = &sB0[lrow * 64 + (tid & 7) * 8];
  bf16* ldsA1 = &sA1[lrow * 64 + (tid & 7) * 8];
  bf16* ldsB1 = &sB1[lrow * 64 + (tid & 7) * 8];

  f32x4 acc[MREP][4] = {};

#define STAGE(t, la, lb) do {                                                   \
    const bf16* As = ((t) < 8) ? pA_x : pA_g;                                   \
    const int ko = ((t) & 7) * 64;                                              \
    _Pragma("unroll")                                                           \
    for (int i = 0; i < MREP / 2; ++i)                                          \
      gl_lds16(As + (size_t)i * 64 * D + ko, (la) + i * 64 * 64);               \
    _Pragma("unroll")                                                           \
    for (int i = 0; i < 4; ++i)                                                 \
      gl_lds16(pB + (size_t)i * 64 * K_TOT + (t) * 64, (lb) + i * 64 * 64);     \
  } while (0)

#define COMPUTE(sa, sb) do {                                                    \
    _Pragma("unroll")                                                           \
    for (int kk = 0; kk < 2; ++kk) {                                            \
      const int cx = ((kk * 4 + fq) ^ (fr & 7)) * 8;                            \
      bf16x8 aF[MREP], bF[4];                                                   \
      _Pragma("unroll")                                                         \
      for (int m = 0; m < MREP; ++m)                                            \
        aF[m] = *(const bf16x8*)&(sa)[(wm * (16 * MREP) + m * 16 + fr) * 64 + cx]; \
      _Pragma("unroll")                                                         \
      for (int nn = 0; nn < 4; ++nn)                                            \
        bF[nn] = *(const bf16x8*)&(sb)[(wn * 64 + nn * 16 + fr) * 64 + cx];     \
      _Pragma("unroll")                                                         \
      for (int m = 0; m < MREP; ++m)                                            \
        _Pragma("unroll")                                                       \
        for (int nn = 0; nn < 4; ++nn)                                          \
          acc[m][nn] = __builtin_amdgcn_mfma_f32_16x16x32_bf16(aF[m], bF[nn], acc[m][nn], 0, 0, 0); \
    }                                                                           \
  } while (0)

  STAGE(0, ldsA0, ldsB0);
  __syncthreads();
#pragma unroll 1
  for (int t = 0; t < 16; t += 2) {
    STAGE(t + 1, ldsA1, ldsB1);
    COMPUTE(sA0, sB0);
    __syncthreads();
    if (t + 2 < 16) STAGE(t + 2, ldsA0, ldsB0);
    COMPUTE(sA1, sB1);
    __syncthreads();
  }
#undef STAGE
#undef COMPUTE

  // epilogue: bias, store h (bf16 or f32), fused column stats (skip pad rows)
  const int rowb = (int)rowA0 + wm * (16 * MREP);
  const int colb = rowB0 + wn * 64;
  float s[4] = {0.f, 0.f, 0.f, 0.f}, q[4] = {0.f, 0.f, 0.f, 0.f};
#pragma unroll
  for (int nn = 0; nn < 4; ++nn) {
    int col = colb + nn * 16 + fr;
    float bv = bias[col];
#pragma unroll
    for (int m = 0; m < MREP; ++m) {
      int row0 = rowb + m * 16 + fq * 4;
#pragma unroll
      for (int r = 0; r < 4; ++r) {
        int row = row0 + r;
        if (row < M) {
          float v = acc[m][nn][r] + bv;
          if (HB) Hb[(size_t)row * D + col] = (bf16)v;
          else    Cf[(size_t)row * D + col] = v;
          s[nn] += v;
          q[nn] += v * v;
        }
      }
    }
  }
#pragma unroll
  for (int nn = 0; nn < 4; ++nn) {
    float sv = s[nn], qv = q[nn];
    sv += __shfl_down(sv, 32); sv += __shfl_down(sv, 16);
    qv += __shfl_down(qv, 32); qv += __shfl_down(qv, 16);
    if (lane < 16) {
      int col = colb + nn * 16 + fr;
      atomicAdd(&stat[col], sv);
      atomicAdd(&stat[D + col], qv);
    }
  }
}

// ---------------- normalize + ReLU, finalize folded in; NT stores (out never re-read) ----------------
template <bool HB>
__global__ void k_apply(const bf16* __restrict__ hb, const float* __restrict__ hf,
                        const float* __restrict__ stat, const float* __restrict__ gamma,
                        const float* __restrict__ beta, float* __restrict__ out,
                        int n, float invn) {
  size_t i = (size_t)blockIdx.x * blockDim.x + threadIdx.x;
  size_t stride = (size_t)gridDim.x * blockDim.x;
  size_t total = (size_t)n * (D / 4);
  f32x4* ov = (f32x4*)out;
  for (; i < total; i += stride) {
    int c4 = ((int)i & 127) * 4;
    float vx, vy, vz, vw;
    if (HB) {
      bf16x4 hv = *(const bf16x4*)&hb[i * 4];
      vx = (float)hv[0]; vy = (float)hv[1]; vz = (float)hv[2]; vw = (float)hv[3];
    } else {
      f32x4 v = ((const f32x4*)hf)[i];
      vx = v[0]; vy = v[1]; vz = v[2]; vw = v[3];
    }
    float4 st = *(const float4*)&stat[c4];
    float4 sq = *(const float4*)&stat[D + c4];
    float4 gm = *(const float4*)&gamma[c4];
    float4 bt = *(const float4*)&beta[c4];
    f32x4 o;
    {
      float mu = st.x * invn, var = sq.x * invn - mu * mu;
      float sc = gm.x * rsqrtf(var + EPS);
      o[0] = fmaxf(vx * sc + (bt.x - mu * sc), 0.f);
    }
    {
      float mu = st.y * invn, var = sq.y * invn - mu * mu;
      float sc = gm.y * rsqrtf(var + EPS);
      o[1] = fmaxf(vy * sc + (bt.y - mu * sc), 0.f);
    }
    {
      float mu = st.z * invn, var = sq.z * invn - mu * mu;
      float sc = gm.z * rsqrtf(var + EPS);
      o[2] = fmaxf(vz * sc + (bt.z - mu * sc), 0.f);
    }
    {
      float mu = st.w * invn, var = sq.w * invn - mu * mu;
      float sc = gm.w * rsqrtf(var + EPS);
      o[3] = fmaxf(vw * sc + (bt.w - mu * sc), 0.f);
    }
    __builtin_nontemporal_store(o, ov + i);
  }
}

extern "C" void kernel_launch(void* const* d_in, const int* in_sizes, int n_in,
                              void* d_out, int out_size, void* d_ws, size_t ws_size,
                              hipStream_t stream) {
  const float* x = (const float*)d_in[0];
  const int* ei = (const int*)d_in[1];
  const float* Wl = (const float*)d_in[2];
  const float* bl = (const float*)d_in[3];
  const float* Wr = (const float*)d_in[4];
  const float* gamma = (const float*)d_in[5];
  const float* beta = (const float*)d_in[6];
  float* out = (float*)d_out;

  const int E = in_sizes[1] / 2;
  const int n = in_sizes[0] / D;  // 100000
  const int Mpad = ((n + 255) / 256) * 256;  // 100096 = 391*256
  const int nb = (n + CHUNK - 1) / CHUNK;    // 98

  char* ws = (char*)d_ws;
  size_t off_b = 0;
  bf16* Xb   = (bf16*)(ws + off_b); off_b += (size_t)Mpad * D * sizeof(bf16);
  bf16* Aggr = (bf16*)(ws + off_b); off_b += (size_t)Mpad * D * sizeof(bf16);
  bf16* Wc   = (bf16*)(ws + off_b); off_b += (size_t)D * K_TOT * sizeof(bf16);
  int* cnt   = (int*)(ws + off_b);  off_b += (size_t)n * sizeof(int);
  int* offs  = (int*)(ws + off_b);  off_b += (size_t)(n + 1) * sizeof(int);
  int* cur   = (int*)(ws + off_b);  off_b += (size_t)n * sizeof(int);
  int* csr   = (int*)(ws + off_b);  off_b += (size_t)E * sizeof(int);
  int* bsum  = (int*)(ws + off_b);  off_b += 512 * sizeof(int);
  int* bbase = (int*)(ws + off_b);  off_b += 512 * sizeof(int);  // unused (kept for layout stability)
  float* stat = (float*)(ws + off_b); off_b += 2 * D * sizeof(float);
  bf16* Hb   = (bf16*)(ws + off_b);
  const size_t need_hb = off_b + (size_t)Mpad * D * sizeof(bf16);
  const bool use_hb = (ws_size >= need_hb);
  (void)bbase;

  const int* srcIdx = ei;
  const int* dstIdx = ei + E;
  const int padGroups = (Mpad - n) * D / 8;
  const float invn = 1.0f / (float)n;

  // Exact-round partition: 384 M-blocks -> 768 tiles = 3 full occupancy rounds;
  // remaining 7 M-blocks as 14 half-height tiles in one short tail launch.
  const int mb256 = Mpad / 256;                 // 391
  int mainMB = (mb256 / 128) * 128;             // 384
  if (mainMB == 0) mainMB = mb256;
  const int tailMB = (Mpad - mainMB * 256) / 128;  // 14
  const int Mbase2 = mainMB * 256;

  k_prep<<<2048, 256, 0, stream>>>(x, Xb, cnt, cur, stat,
                                   Xb + (size_t)n * D, Aggr + (size_t)n * D,
                                   Wl, Wr, Wc,
                                   n, padGroups, (size_t)n * D / 8);
  k_degree<<<2048, 256, 0, stream>>>(dstIdx, cnt, E);
  k_blocksum<<<nb, 256, 0, stream>>>(cnt, bsum, n);
  k_offsets<<<nb, 256, 0, stream>>>(cnt, bsum, offs, n, E);
  k_fill<<<2048, 256, 0, stream>>>(srcIdx, dstIdx, offs, cur, csr, E);
  k_gather<<<(n + 3) / 4, 256, 0, stream>>>(Xb, offs, csr, Aggr, n);
  if (use_hb) {
    k_gemm<8, true><<<mainMB * 2, 512, 0, stream>>>(Xb, Aggr, Wc, bl, Hb, out, stat, 0, n);
    if (tailMB)
      k_gemm<4, true><<<tailMB * 2, 512, 0, stream>>>(Xb, Aggr, Wc, bl, Hb, out, stat, Mbase2, n);
    k_apply<true><<<2048, 256, 0, stream>>>(Hb, out, stat, gamma, beta, out, n, invn);
  } else {
    k_gemm<8, false><<<mainMB * 2, 512, 0, stream>>>(Xb, Aggr, Wc, bl, Hb, out, stat, 0, n);
    if (tailMB)
      k_gemm<4, false><<<tailMB * 2, 512, 0, stream>>>(Xb, Aggr, Wc, bl, Hb, out, stat, Mbase2, n);
    k_apply<false><<<2048, 256, 0, stream>>>(Hb, out, stat, gamma, beta, out, n, invn);
  }
}